// Round 1
// baseline (270.265 us; speedup 1.0000x reference)
//
#include <hip/hip_runtime.h>

#define T_LEN 200
#define F_IN  32
#define CH    25   // timesteps per LDS chunk; 200 = 8 * 25
#define GPB   8    // batch elements (32-lane groups) per 256-thread block

// ds_swizzle BitMode: src_lane = ((lane & and) | or) ^ xor, within each 32-lane half.
// pattern = (xor<<10) | (or<<5) | and
template <int PAT>
__device__ __forceinline__ float swz(float v) {
    return __int_as_float(__builtin_amdgcn_ds_swizzle(__float_as_int(v), PAT));
}

__device__ __forceinline__ float sigm(float x) {
    // 1/(1+e^-x); exp overflow -> inf -> rcp -> 0 (correct saturation)
    return __builtin_amdgcn_rcpf(1.0f + __expf(-x));
}

__launch_bounds__(256, 2)
__global__ void mono_lstm_kernel(const float* __restrict__ x,
                                 const float* __restrict__ z0,
                                 const float* __restrict__ W_ih,
                                 const float* __restrict__ W_hh,
                                 const float* __restrict__ b_ih,
                                 const float* __restrict__ b_hh,
                                 const float* __restrict__ W1,
                                 const float* __restrict__ b1,
                                 const float* __restrict__ W2,
                                 const float* __restrict__ b2,
                                 float* __restrict__ out) {
    __shared__ float xs[GPB * CH * F_IN];  // 25.6 KB

    const int tid  = threadIdx.x;
    const int grp  = tid >> 5;   // batch group within block
    const int lane = tid & 31;   // gate row g for this lane
    const int b    = blockIdx.x * GPB + grp;

    // Per-lane weights: lane owns gate row `lane` of W_ih (33 cols) and W_hh (8 cols).
    float wih[33];
#pragma unroll
    for (int k = 0; k < 33; ++k) wih[k] = W_ih[lane * 33 + k];
    float whh[8];
#pragma unroll
    for (int k = 0; k < 8; ++k) whh[k] = W_hh[lane * 8 + k];
    const float bias = b_ih[lane] + b_hh[lane];

    // Head, distributed: lane m = lane&7 (<5) owns row m of W1.
    const int m = lane & 7;
    float w1r[8];
    float b1r = 0.0f;
    if (m < 5) {
#pragma unroll
        for (int k = 0; k < 8; ++k) w1r[k] = W1[m * 8 + k];
        b1r = b1[m];
    } else {
#pragma unroll
        for (int k = 0; k < 8; ++k) w1r[k] = 0.0f;
    }
    const float w20 = W2[0], w21 = W2[1], w22 = W2[2], w23 = W2[3], w24 = W2[4];
    const float b2v = b2[0];

    const bool isG = ((lane >> 3) == 2);  // rows 16..23 use tanh

    float c = 0.0f;  // holds c_{lane&7}, replicated x4 across the group
    float h0 = 0.f, h1 = 0.f, h2 = 0.f, h3 = 0.f, h4 = 0.f, h5 = 0.f, h6 = 0.f, h7 = 0.f;
    float z = z0[b];
    float zbuf = 0.0f;

    const float* xg   = x + (size_t)blockIdx.x * GPB * T_LEN * F_IN;
    float*       outg = out + (size_t)b * T_LEN;

    for (int chunk = 0; chunk < T_LEN / CH; ++chunk) {
        const int t0 = chunk * CH;
        __syncthreads();  // previous chunk's LDS reads done before overwrite
        // Stage x[block batches][t0..t0+CH)[0..32) into LDS, coalesced float4.
        for (int e = tid * 4; e < GPB * CH * F_IN; e += 256 * 4) {
            const int gi  = e / (CH * F_IN);
            const int rem = e - gi * (CH * F_IN);
            const int tt  = rem >> 5;
            const int f   = rem & 31;
            const float4 v = *(const float4*)&xg[(size_t)gi * T_LEN * F_IN +
                                                 (size_t)(t0 + tt) * F_IN + f];
            *(float4*)&xs[e] = v;
        }
        __syncthreads();

        const float4* xrow = (const float4*)&xs[grp * CH * F_IN];
        for (int tt = 0; tt < CH; ++tt) {
            // gate pre-activation: bias + W_ih[:, :32].x_t + W_ih[:,32]*z + W_hh.h
            float acc = fmaf(wih[32], z, bias);
            const float4* xp = xrow + tt * 8;
#pragma unroll
            for (int q = 0; q < 8; ++q) {
                const float4 xv = xp[q];  // broadcast ds_read_b128
                acc = fmaf(wih[4 * q + 0], xv.x, acc);
                acc = fmaf(wih[4 * q + 1], xv.y, acc);
                acc = fmaf(wih[4 * q + 2], xv.z, acc);
                acc = fmaf(wih[4 * q + 3], xv.w, acc);
            }
            acc = fmaf(whh[0], h0, acc);
            acc = fmaf(whh[1], h1, acc);
            acc = fmaf(whh[2], h2, acc);
            acc = fmaf(whh[3], h3, acc);
            acc = fmaf(whh[4], h4, acc);
            acc = fmaf(whh[5], h5, acc);
            acc = fmaf(whh[6], h6, acc);
            acc = fmaf(whh[7], h7, acc);

            // activation: sigmoid for i,f,o rows; tanh (=2*sig(2x)-1) for g rows
            const float tin = isG ? 2.0f * acc : acc;
            const float s   = sigm(tin);
            const float a   = isG ? fmaf(2.0f, s, -1.0f) : s;

            // gather i_j, f_j, g_j, o_j for j = lane&7 (replicated, divergence-free)
            const float iv = swz<((0 << 5) | 7)>(a);
            const float fv = swz<((8 << 5) | 7)>(a);
            const float gv = swz<((16 << 5) | 7)>(a);
            const float ov = swz<((24 << 5) | 7)>(a);
            c = fmaf(fv, c, iv * gv);
            const float tc = fmaf(2.0f, sigm(2.0f * c), -1.0f);  // tanh(c)
            const float hn = ov * tc;                             // h_{lane&7}

            // broadcast full h vector to every lane (needed for W_hh and head)
            h0 = swz<(0 << 5)>(hn);
            h1 = swz<(1 << 5)>(hn);
            h2 = swz<(2 << 5)>(hn);
            h3 = swz<(3 << 5)>(hn);
            h4 = swz<(4 << 5)>(hn);
            h5 = swz<(5 << 5)>(hn);
            h6 = swz<(6 << 5)>(hn);
            h7 = swz<(7 << 5)>(hn);

            // head: d_m = relu(W1[m].h + b1[m]) on lane m; delta = relu(W2.d + b2)
            float d = b1r;
            d = fmaf(w1r[0], h0, d);
            d = fmaf(w1r[1], h1, d);
            d = fmaf(w1r[2], h2, d);
            d = fmaf(w1r[3], h3, d);
            d = fmaf(w1r[4], h4, d);
            d = fmaf(w1r[5], h5, d);
            d = fmaf(w1r[6], h6, d);
            d = fmaf(w1r[7], h7, d);
            d = fmaxf(d, 0.0f);

            float delta = b2v;
            delta = fmaf(w20, swz<(0 << 5)>(d), delta);
            delta = fmaf(w21, swz<(1 << 5)>(d), delta);
            delta = fmaf(w22, swz<(2 << 5)>(d), delta);
            delta = fmaf(w23, swz<(3 << 5)>(d), delta);
            delta = fmaf(w24, swz<(4 << 5)>(d), delta);
            delta = fmaxf(delta, 0.0f);
            z += delta;

            // buffer z of step tt into lane tt's zbuf for a coalesced chunk store
            zbuf = (lane == tt) ? z : zbuf;
        }
        if (lane < CH) outg[t0 + lane] = zbuf;
    }
}

extern "C" void kernel_launch(void* const* d_in, const int* in_sizes, int n_in,
                              void* d_out, int out_size, void* d_ws, size_t ws_size,
                              hipStream_t stream) {
    const float* x    = (const float*)d_in[0];
    const float* z0   = (const float*)d_in[1];
    const float* W_ih = (const float*)d_in[2];
    const float* W_hh = (const float*)d_in[3];
    const float* b_ih = (const float*)d_in[4];
    const float* b_hh = (const float*)d_in[5];
    const float* W1   = (const float*)d_in[6];
    const float* b1   = (const float*)d_in[7];
    const float* W2   = (const float*)d_in[8];
    const float* b2   = (const float*)d_in[9];
    float* out = (float*)d_out;

    const int B = in_sizes[1];  // z0 has B elements
    dim3 grid(B / GPB), block(256);
    hipLaunchKernelGGL(mono_lstm_kernel, grid, block, 0, stream,
                       x, z0, W_ih, W_hh, b_ih, b_hh, W1, b1, W2, b2, out);
}

// Round 2
// 238.606 us; speedup vs baseline: 1.1327x; 1.1327x over previous
//
#include <hip/hip_runtime.h>

#define T_LEN 200
#define F_IN  32
#define CH    25   // timesteps per chunk; 200 = 8 * 25
#define GPB   8    // batch groups (32 lanes each) per 256-thread block

// ---- cross-lane helpers -------------------------------------------------
#define QP(a,b,c,d) ((a)|((b)<<2)|((c)<<4)|((d)<<6))
#define DPP_ROW_MIRROR       0x140   // lane -> lane^15 within row of 16
#define DPP_ROW_HALF_MIRROR  0x141   // lane -> lane^7  within row of 16

template <int CTRL>
__device__ __forceinline__ float dppf(float v) {
    return __int_as_float(__builtin_amdgcn_update_dpp(
        0, __float_as_int(v), CTRL, 0xF, 0xF, true));
}
// ds_swizzle BitMode: src = ((lane&and)|or)^xor ; pattern=(xor<<10)|(or<<5)|and
template <int PAT>
__device__ __forceinline__ float swzf(float v) {
    return __int_as_float(__builtin_amdgcn_ds_swizzle(__float_as_int(v), PAT));
}

__device__ __forceinline__ float sigm(float x) {
    return __builtin_amdgcn_rcpf(1.0f + __expf(-x));  // saturates correctly
}
__device__ __forceinline__ float tanhf_fast(float x) {
    return fmaf(2.0f, sigm(x + x), -1.0f);
}
__device__ __forceinline__ float2 f2fma(float2 a, float2 b, float2 c) {
    return make_float2(fmaf(a.x, b.x, c.x), fmaf(a.y, b.y, c.y));
}
__device__ __forceinline__ float2 f2mul(float2 a, float2 b) {
    return make_float2(a.x * b.x, a.y * b.y);
}

__launch_bounds__(256, 2)
__global__ void mono_lstm_kernel(const float* __restrict__ x,
                                 const float* __restrict__ z0,
                                 const float* __restrict__ W_ih,
                                 const float* __restrict__ W_hh,
                                 const float* __restrict__ b_ih,
                                 const float* __restrict__ b_hh,
                                 const float* __restrict__ W1,
                                 const float* __restrict__ b1,
                                 const float* __restrict__ W2,
                                 const float* __restrict__ b2,
                                 float* __restrict__ out) {
    __shared__ float xs[GPB * CH * F_IN];  // 25.6 KB

    const int tid  = threadIdx.x;
    const int grp  = tid >> 5;
    const int lane = tid & 31;
    const int j    = lane >> 2;  // hidden unit (quad index)
    const int g    = lane & 3;   // gate: 0=i 1=f 2=g 3=o
    const int row  = 8 * g + j;  // torch gate-row owned by this lane
    const int b    = blockIdx.x * GPB + grp;

    // Input-proj weights, quad-K-split: slot q covers row 8*(g^q)+j, cols [8g,8g+8)
    float2 wq[4][4];
#pragma unroll
    for (int q = 0; q < 4; ++q) {
        const int rq = 8 * (g ^ q) + j;
#pragma unroll
        for (int k2 = 0; k2 < 4; ++k2)
            wq[q][k2] = make_float2(W_ih[rq * 33 + 8 * g + 2 * k2],
                                    W_ih[rq * 33 + 8 * g + 2 * k2 + 1]);
    }
    const float wihz = W_ih[row * 33 + 32];
    const float bias = b_ih[row] + b_hh[row];

    // Recurrent weights in xor-gather order: ha[k] will hold h_{j^k}
    float whhp[8];
#pragma unroll
    for (int k = 0; k < 8; ++k) whhp[k] = W_hh[row * 8 + (j ^ k)];

    // Head: lane computes d_{m=g} (x) and d_4 (y), xor-permuted cols
    float2 w1d[8];
#pragma unroll
    for (int k = 0; k < 8; ++k)
        w1d[k] = make_float2(W1[g * 8 + (j ^ k)], W1[4 * 8 + (j ^ k)]);
    const float2 b1d = make_float2(b1[g], b1[4]);
    const float w20 = W2[0], w21 = W2[1], w22 = W2[2], w23 = W2[3], w24 = W2[4];
    const float b2v = b2[0];

    const bool isG = (g == 2);

    float c = 0.0f;
    float ha0 = 0.f, ha1 = 0.f, ha2 = 0.f, ha3 = 0.f,
          ha4 = 0.f, ha5 = 0.f, ha6 = 0.f, ha7 = 0.f;  // h_{j^k}
    float z = z0[b];
    float zbuf = 0.0f;
    float pre[CH];

    const float* xg   = x + (size_t)blockIdx.x * GPB * T_LEN * F_IN;
    float*       outg = out + (size_t)b * T_LEN;

    for (int chunk = 0; chunk < T_LEN / CH; ++chunk) {
        const int t0 = chunk * CH;
        __syncthreads();
        for (int e = tid * 4; e < GPB * CH * F_IN; e += 256 * 4) {
            const int gi  = e / (CH * F_IN);
            const int rem = e - gi * (CH * F_IN);
            const int tt  = rem >> 5;
            const int f   = rem & 31;
            *(float4*)&xs[e] = *(const float4*)&xg[(size_t)gi * T_LEN * F_IN +
                                                   (size_t)(t0 + tt) * F_IN + f];
        }
        __syncthreads();

        // ---- pre-phase: pre[tt] = bias + W_ih[row,:32] . x_t  (ILP-rich) ----
        const float* xrow = &xs[grp * CH * F_IN + 8 * g];
#pragma unroll
        for (int tt = 0; tt < CH; ++tt) {
            const float4 xa = *(const float4*)&xrow[tt * F_IN];
            const float4 xb = *(const float4*)&xrow[tt * F_IN + 4];
            const float2 x0 = make_float2(xa.x, xa.y), x1 = make_float2(xa.z, xa.w);
            const float2 x2 = make_float2(xb.x, xb.y), x3 = make_float2(xb.z, xb.w);
            float2 p0 = f2fma(wq[0][0], x0, f2fma(wq[0][1], x1,
                        f2fma(wq[0][2], x2, f2mul(wq[0][3], x3))));
            float2 p1 = f2fma(wq[1][0], x0, f2fma(wq[1][1], x1,
                        f2fma(wq[1][2], x2, f2mul(wq[1][3], x3))));
            float2 p2 = f2fma(wq[2][0], x0, f2fma(wq[2][1], x1,
                        f2fma(wq[2][2], x2, f2mul(wq[2][3], x3))));
            float2 p3 = f2fma(wq[3][0], x0, f2fma(wq[3][1], x1,
                        f2fma(wq[3][2], x2, f2mul(wq[3][3], x3))));
            float s0 = p0.x + p0.y, s1 = p1.x + p1.y;
            float s2 = p2.x + p2.y, s3 = p3.x + p3.y;
            // quad reduce (rows align via slot^lane xor structure)
            s0 += dppf<QP(1, 0, 3, 2)>(s1);   // + lane^1's slot1 (same row)
            s2 += dppf<QP(1, 0, 3, 2)>(s3);
            s0 += dppf<QP(2, 3, 0, 1)>(s2);   // + lane^2's slot2 pair-sum
            pre[tt] = bias + s0;
        }

        // ---- serial recurrence ----
#pragma unroll
        for (int tt = 0; tt < CH; ++tt) {
            float a0 = fmaf(whhp[0], ha0, pre[tt]);
            float a1 = whhp[1] * ha1;
            a0 = fmaf(whhp[2], ha2, a0);  a1 = fmaf(whhp[3], ha3, a1);
            a0 = fmaf(whhp[4], ha4, a0);  a1 = fmaf(whhp[5], ha5, a1);
            a0 = fmaf(whhp[6], ha6, a0);  a1 = fmaf(whhp[7], ha7, a1);
            float acc = fmaf(wihz, z, a0 + a1);

            const float tin = isG ? acc + acc : acc;
            const float s   = sigm(tin);
            const float a   = isG ? fmaf(2.0f, s, -1.0f) : s;

            // i,f,g,o of unit j via quad broadcasts
            const float iv = dppf<QP(0, 0, 0, 0)>(a);
            const float fv = dppf<QP(1, 1, 1, 1)>(a);
            const float gv = dppf<QP(2, 2, 2, 2)>(a);
            const float ov = dppf<QP(3, 3, 3, 3)>(a);
            c = fmaf(fv, c, iv * gv);
            const float hn = ov * tanhf_fast(c);

            // gather h_{j^k}: 1 swizzle (xor16) + 6 DPP involutions
            const float hx = swzf<0x401F>(hn);                 // h_{j^4}
            ha0 = hn;
            ha1 = dppf<DPP_ROW_HALF_MIRROR>(hn);               // h_{j^1}
            const float t3 = dppf<DPP_ROW_MIRROR>(hn);         // h_{j^3}
            ha2 = dppf<DPP_ROW_HALF_MIRROR>(t3);               // h_{j^2}
            ha3 = t3;
            ha4 = hx;
            ha5 = dppf<DPP_ROW_HALF_MIRROR>(hx);               // h_{j^5}
            const float t7 = dppf<DPP_ROW_MIRROR>(hx);         // h_{j^7}
            ha6 = dppf<DPP_ROW_HALF_MIRROR>(t7);               // h_{j^6}
            ha7 = t7;

            // head: d2 = (d_g, d_4), two fma chains for ILP
            float2 dA = f2fma(w1d[0], make_float2(ha0, ha0),
                       f2fma(w1d[2], make_float2(ha2, ha2),
                       f2fma(w1d[4], make_float2(ha4, ha4),
                       f2fma(w1d[6], make_float2(ha6, ha6), b1d))));
            float2 dB = f2fma(w1d[1], make_float2(ha1, ha1),
                       f2fma(w1d[3], make_float2(ha3, ha3),
                       f2fma(w1d[5], make_float2(ha5, ha5),
                       f2mul(w1d[7], make_float2(ha7, ha7)))));
            float dg = fmaxf(dA.x + dB.x, 0.0f);   // d_{m=g}
            float d4 = fmaxf(dA.y + dB.y, 0.0f);   // d_4

            float delta = fmaf(w24, d4, b2v);
            delta = fmaf(w20, dppf<QP(0, 0, 0, 0)>(dg), delta);
            delta = fmaf(w21, dppf<QP(1, 1, 1, 1)>(dg), delta);
            delta = fmaf(w22, dppf<QP(2, 2, 2, 2)>(dg), delta);
            delta = fmaf(w23, dppf<QP(3, 3, 3, 3)>(dg), delta);
            delta = fmaxf(delta, 0.0f);
            z += delta;

            zbuf = (lane == tt) ? z : zbuf;
        }
        if (lane < CH) outg[t0 + lane] = zbuf;
    }
}

extern "C" void kernel_launch(void* const* d_in, const int* in_sizes, int n_in,
                              void* d_out, int out_size, void* d_ws, size_t ws_size,
                              hipStream_t stream) {
    const float* x    = (const float*)d_in[0];
    const float* z0   = (const float*)d_in[1];
    const float* W_ih = (const float*)d_in[2];
    const float* W_hh = (const float*)d_in[3];
    const float* b_ih = (const float*)d_in[4];
    const float* b_hh = (const float*)d_in[5];
    const float* W1   = (const float*)d_in[6];
    const float* b1   = (const float*)d_in[7];
    const float* W2   = (const float*)d_in[8];
    const float* b2   = (const float*)d_in[9];
    float* out = (float*)d_out;

    const int B = in_sizes[1];
    dim3 grid(B / GPB), block(256);
    hipLaunchKernelGGL(mono_lstm_kernel, grid, block, 0, stream,
                       x, z0, W_ih, W_hh, b_ih, b_hh, W1, b1, W2, b2, out);
}